// Round 2
// baseline (1307.127 us; speedup 1.0000x reference)
//
#include <hip/hip_runtime.h>
#include <cfloat>

#define B_Q 2048
#define N_T 65536
#define DIM 384

#define BM 128
#define BN 128
#define BK 16
#define PAD 132                       // 132*4B = 528B rows: 16B-aligned, ~2-way bank conflicts only
#define TILES_PER_STRIP 8
#define STRIP_N (BN * TILES_PER_STRIP)  // 1024 train points per block
#define NSTRIPS (N_T / STRIP_N)         // 64
#define NKT (DIM / BK)                  // 24

// Kernel 0: tt[j] = ||X_train[j]||^2  (one wave per row, stride-64 coalesced)
__global__ void tt_kernel(const float* __restrict__ Xt, float* __restrict__ tt) {
  const int wave = threadIdx.x >> 6;
  const int lane = threadIdx.x & 63;
  const int row = blockIdx.x * 4 + wave;
  const float* p = Xt + (size_t)row * DIM;
  float s = 0.f;
#pragma unroll
  for (int i = 0; i < DIM / 64; ++i) {
    float v = p[lane + 64 * i];
    s = fmaf(v, v, s);
  }
#pragma unroll
  for (int off = 32; off > 0; off >>= 1) s += __shfl_xor(s, off, 64);
  if (lane == 0) tt[row] = s;
}

// Kernel 1: fused cross-GEMM + partial argmin.
// Block = 256 threads (16x16), tile 128 queries x 128 trains, 8x8 micro-tile.
// Each block scans a strip of 1024 train points, emits per-query (minval, minidx).
__global__ __launch_bounds__(256) void dist_kernel(
    const float* __restrict__ x, const float* __restrict__ Xt,
    const float* __restrict__ tt, float* __restrict__ pval, int* __restrict__ pidx) {
  __shared__ float As[BK][PAD];
  __shared__ float Bs[BK][PAD];

  const int t = threadIdx.x;
  const int tx = t & 15;
  const int ty = t >> 4;
  const int qbase = blockIdx.x * BM;
  const int strip = blockIdx.y;
  const int nstripbase = strip * STRIP_N;

  float bestv[8];
  int besti[8];
#pragma unroll
  for (int i = 0; i < 8; ++i) { bestv[i] = FLT_MAX; besti[i] = 0x7fffffff; }

  for (int tile = 0; tile < TILES_PER_STRIP; ++tile) {
    const int nbase = nstripbase + tile * BN;
    float acc[8][8];
#pragma unroll
    for (int i = 0; i < 8; ++i)
#pragma unroll
      for (int j = 0; j < 8; ++j) acc[i][j] = 0.f;

    for (int kt = 0; kt < NKT; ++kt) {
      const int kbase = kt * BK;
      __syncthreads();
      // stage A (queries) and B (trains) tiles, transposed to k-major
#pragma unroll
      for (int it = 0; it < 2; ++it) {
        int idx = t + it * 256;
        int row = idx >> 2;
        int k4 = (idx & 3) << 2;
        float4 va = *(const float4*)(x + (size_t)(qbase + row) * DIM + kbase + k4);
        As[k4 + 0][row] = va.x; As[k4 + 1][row] = va.y;
        As[k4 + 2][row] = va.z; As[k4 + 3][row] = va.w;
        float4 vb = *(const float4*)(Xt + (size_t)(nbase + row) * DIM + kbase + k4);
        Bs[k4 + 0][row] = vb.x; Bs[k4 + 1][row] = vb.y;
        Bs[k4 + 2][row] = vb.z; Bs[k4 + 3][row] = vb.w;
      }
      __syncthreads();
#pragma unroll
      for (int kk = 0; kk < BK; ++kk) {
        float4 a0 = *(const float4*)&As[kk][ty * 4];
        float4 a1 = *(const float4*)&As[kk][64 + ty * 4];
        float4 b0 = *(const float4*)&Bs[kk][tx * 4];
        float4 b1 = *(const float4*)&Bs[kk][64 + tx * 4];
        float a[8] = {a0.x, a0.y, a0.z, a0.w, a1.x, a1.y, a1.z, a1.w};
        float b[8] = {b0.x, b0.y, b0.z, b0.w, b1.x, b1.y, b1.z, b1.w};
#pragma unroll
        for (int i = 0; i < 8; ++i)
#pragma unroll
          for (int j = 0; j < 8; ++j) acc[i][j] = fmaf(a[i], b[j], acc[i][j]);
      }
    }

    // s = tt - 2*cross ; update running per-row argmin (cols scanned in increasing order)
    int cols[8];
    float ttv[8];
#pragma unroll
    for (int j = 0; j < 8; ++j) {
      cols[j] = nbase + (j < 4 ? tx * 4 + j : 64 + tx * 4 + (j - 4));
      ttv[j] = tt[cols[j]];
    }
#pragma unroll
    for (int i = 0; i < 8; ++i) {
#pragma unroll
      for (int j = 0; j < 8; ++j) {
        float s = fmaf(-2.f, acc[i][j], ttv[j]);
        if (s < bestv[i] || (s == bestv[i] && cols[j] < besti[i])) {
          bestv[i] = s; besti[i] = cols[j];
        }
      }
    }
  }

  // reduce across the 16 tx-lanes sharing each query row (lanes (ty&3)*16+tx)
#pragma unroll
  for (int i = 0; i < 8; ++i) {
    float v = bestv[i];
    int ix = besti[i];
#pragma unroll
    for (int off = 1; off < 16; off <<= 1) {
      float ov = __shfl_xor(v, off, 64);
      int oi = __shfl_xor(ix, off, 64);
      if (ov < v || (ov == v && oi < ix)) { v = ov; ix = oi; }
    }
    if (tx == 0) {
      int row = qbase + (i < 4 ? ty * 4 + i : 64 + ty * 4 + (i - 4));
      pval[(size_t)row * NSTRIPS + strip] = v;
      pidx[(size_t)row * NSTRIPS + strip] = ix;
    }
  }
}

// Kernel 2: final 64-way argmin per query + gather Y_train[nearest]
__global__ void reduce_kernel(const float* __restrict__ pval, const int* __restrict__ pidx,
                              const float* __restrict__ Y, float* __restrict__ out) {
  const int wave = threadIdx.x >> 6;
  const int lane = threadIdx.x & 63;
  const int q = blockIdx.x * 4 + wave;
  float v = pval[(size_t)q * NSTRIPS + lane];
  int ix = pidx[(size_t)q * NSTRIPS + lane];
#pragma unroll
  for (int off = 32; off > 0; off >>= 1) {
    float ov = __shfl_xor(v, off, 64);
    int oi = __shfl_xor(ix, off, 64);
    if (ov < v || (ov == v && oi < ix)) { v = ov; ix = oi; }
  }
  if (lane < 24) out[(size_t)q * 24 + lane] = Y[(size_t)ix * 24 + lane];
}

extern "C" void kernel_launch(void* const* d_in, const int* in_sizes, int n_in,
                              void* d_out, int out_size, void* d_ws, size_t ws_size,
                              hipStream_t stream) {
  const float* x  = (const float*)d_in[0];   // [2048,24,16] -> flat [2048,384]
  const float* Xt = (const float*)d_in[1];   // [65536,384]
  const float* Y  = (const float*)d_in[2];   // [65536,24,1]
  float* out = (float*)d_out;                // [2048,24,1]

  float* tt   = (float*)d_ws;                         // 65536 floats
  float* pval = tt + N_T;                             // 2048*64 floats
  int*   pidx = (int*)(pval + (size_t)B_Q * NSTRIPS); // 2048*64 ints

  tt_kernel<<<N_T / 4, 256, 0, stream>>>(Xt, tt);
  dist_kernel<<<dim3(B_Q / BM, NSTRIPS), 256, 0, stream>>>(x, Xt, tt, pval, pidx);
  reduce_kernel<<<B_Q / 4, 256, 0, stream>>>(pval, pidx, Y, out);
}

// Round 6
// 514.117 us; speedup vs baseline: 2.5425x; 2.5425x over previous
//
#include <hip/hip_runtime.h>
#include <cfloat>

#define B_Q 2048
#define N_T 65536
#define DIM 384

typedef __attribute__((ext_vector_type(8))) _Float16 f16x8;
typedef __attribute__((ext_vector_type(4))) float f32x4;

__device__ __forceinline__ void gload16(const void* g, void* l) {
  __builtin_amdgcn_global_load_lds(
      (const __attribute__((address_space(1))) void*)g,
      (__attribute__((address_space(3))) void*)l, 16, 0, 0);
}

// ---- prep: fp32 -> (hi, lo) fp16 split, 8 elems/thread -------------------
__global__ void split_kernel(const float* __restrict__ in, _Float16* __restrict__ hi,
                             _Float16* __restrict__ lo, int n8) {
  int i = blockIdx.x * 256 + threadIdx.x;
  if (i >= n8) return;
  float4 a = ((const float4*)in)[2 * i];
  float4 b = ((const float4*)in)[2 * i + 1];
  float v[8] = {a.x, a.y, a.z, a.w, b.x, b.y, b.z, b.w};
  f16x8 h, l;
#pragma unroll
  for (int j = 0; j < 8; ++j) {
    _Float16 hj = (_Float16)v[j];
    h[j] = hj;
    l[j] = (_Float16)(v[j] - (float)hj);
  }
  *(f16x8*)(hi + 8 * (size_t)i) = h;
  *(f16x8*)(lo + 8 * (size_t)i) = l;
}

// ---- tt[j] = ||X_train[j]||^2 (one wave per row) -------------------------
__global__ void tt_kernel(const float* __restrict__ Xt, float* __restrict__ tt) {
  const int wave = threadIdx.x >> 6;
  const int lane = threadIdx.x & 63;
  const int row = blockIdx.x * 4 + wave;
  const float* p = Xt + (size_t)row * DIM;
  float s = 0.f;
#pragma unroll
  for (int i = 0; i < DIM / 64; ++i) {
    float v = p[lane + 64 * i];
    s = fmaf(v, v, s);
  }
#pragma unroll
  for (int off = 32; off > 0; off >>= 1) s += __shfl_xor(s, off, 64);
  if (lane == 0) tt[row] = s;
}

// ---- fused MFMA cross-GEMM + partial argmin ------------------------------
// 128x128 tile, BK=32, 4 waves (2m x 2n), each wave 64x64 via 4x4 16x16 frags.
// fp32-accurate via fp16 split: x.t = xh.th + xh.tl + xl.th  (3 MFMAs).
// Each block scans 8 tiles (1024 trains); emits (minval,minidx) per query
// per (strip, wave-n-half): partial stripe width = 64 strips * 2 = 128.
__global__ __launch_bounds__(256, 2) void dist_mfma(
    const _Float16* __restrict__ xh, const _Float16* __restrict__ xl,
    const _Float16* __restrict__ th, const _Float16* __restrict__ tl,
    const float* __restrict__ tt, float* __restrict__ pval, int* __restrict__ pidx) {
  __shared__ _Float16 Ah[128][32];
  __shared__ _Float16 Al[128][32];
  __shared__ _Float16 Bh[128][32];
  __shared__ _Float16 Bl[128][32];

  const int t = threadIdx.x;
  const int lane = t & 63;
  const int wid = t >> 6;
  const int wm = wid >> 1, wn = wid & 1;
  const int r15 = lane & 15, g = lane >> 4;
  const int qbase = blockIdx.x * 128;
  const int strip = blockIdx.y;

  // staging geometry: linear index li = it*256+t -> row=li>>2, chunk=li&3
  const int srow = t >> 2;
  const int schunk = t & 3;
  const size_t aoff0 = (size_t)(qbase + srow) * DIM + schunk * 8;
  const size_t aoff1 = aoff0 + (size_t)64 * DIM;
  char* ldsA = (char*)&Ah[0][0] + t * 16;
  char* ldsAl = (char*)&Al[0][0] + t * 16;
  char* ldsB = (char*)&Bh[0][0] + t * 16;
  char* ldsBl = (char*)&Bl[0][0] + t * 16;

  float bestv[4][4];
  int besti[4][4];
#pragma unroll
  for (int mf = 0; mf < 4; ++mf)
#pragma unroll
    for (int j = 0; j < 4; ++j) { bestv[mf][j] = FLT_MAX; besti[mf][j] = 0x7fffffff; }

  for (int tile = 0; tile < 8; ++tile) {
    const int nbase = strip * 1024 + tile * 128;
    const size_t boff0 = (size_t)(nbase + srow) * DIM + schunk * 8;
    const size_t boff1 = boff0 + (size_t)64 * DIM;

    f32x4 acc[4][4];
#pragma unroll
    for (int mf = 0; mf < 4; ++mf)
#pragma unroll
      for (int nf = 0; nf < 4; ++nf) acc[mf][nf] = (f32x4){0.f, 0.f, 0.f, 0.f};

    for (int kt = 0; kt < DIM / 32; ++kt) {
      const int ko = kt * 32;
      __syncthreads();
      gload16(xh + aoff0 + ko, ldsA);
      gload16(xh + aoff1 + ko, ldsA + 4096);
      gload16(xl + aoff0 + ko, ldsAl);
      gload16(xl + aoff1 + ko, ldsAl + 4096);
      gload16(th + boff0 + ko, ldsB);
      gload16(th + boff1 + ko, ldsB + 4096);
      gload16(tl + boff0 + ko, ldsBl);
      gload16(tl + boff1 + ko, ldsBl + 4096);
      __syncthreads();

      const _Float16* pA = &Ah[wm * 64 + r15][g * 8];
      const _Float16* pAl = &Al[wm * 64 + r15][g * 8];
      const _Float16* pB = &Bh[wn * 64 + r15][g * 8];
      const _Float16* pBl = &Bl[wn * 64 + r15][g * 8];
      f16x8 a_h[4], a_l[4];
#pragma unroll
      for (int mf = 0; mf < 4; ++mf) {
        a_h[mf] = *(const f16x8*)(pA + mf * 512);
        a_l[mf] = *(const f16x8*)(pAl + mf * 512);
      }
#pragma unroll
      for (int nf = 0; nf < 4; ++nf) {
        f16x8 b_h = *(const f16x8*)(pB + nf * 512);
        f16x8 b_l = *(const f16x8*)(pBl + nf * 512);
#pragma unroll
        for (int mf = 0; mf < 4; ++mf) {
          acc[mf][nf] = __builtin_amdgcn_mfma_f32_16x16x32_f16(a_h[mf], b_h, acc[mf][nf], 0, 0, 0);
          acc[mf][nf] = __builtin_amdgcn_mfma_f32_16x16x32_f16(a_h[mf], b_l, acc[mf][nf], 0, 0, 0);
          acc[mf][nf] = __builtin_amdgcn_mfma_f32_16x16x32_f16(a_l[mf], b_h, acc[mf][nf], 0, 0, 0);
        }
      }
    }

    // epilogue: s = tt - 2*cross, merge into running argmin
    int ncol[4];
    float ttv[4];
#pragma unroll
    for (int nf = 0; nf < 4; ++nf) {
      ncol[nf] = nbase + wn * 64 + nf * 16 + r15;
      ttv[nf] = tt[ncol[nf]];
    }
#pragma unroll
    for (int mf = 0; mf < 4; ++mf)
#pragma unroll
      for (int nf = 0; nf < 4; ++nf)
#pragma unroll
        for (int j = 0; j < 4; ++j) {
          float s = fmaf(-2.f, acc[mf][nf][j], ttv[nf]);
          if (s < bestv[mf][j] || (s == bestv[mf][j] && ncol[nf] < besti[mf][j])) {
            bestv[mf][j] = s;
            besti[mf][j] = ncol[nf];
          }
        }
  }

  // reduce across the 16 n-lanes of each 16-lane group; write partials
#pragma unroll
  for (int mf = 0; mf < 4; ++mf)
#pragma unroll
    for (int j = 0; j < 4; ++j) {
      float v = bestv[mf][j];
      int ix = besti[mf][j];
#pragma unroll
      for (int off = 1; off < 16; off <<= 1) {
        float ov = __shfl_xor(v, off, 64);
        int oi = __shfl_xor(ix, off, 64);
        if (ov < v || (ov == v && oi < ix)) { v = ov; ix = oi; }
      }
      if (r15 == 0) {
        int m = qbase + wm * 64 + mf * 16 + g * 4 + j;
        pval[(size_t)m * 128 + strip * 2 + wn] = v;
        pidx[(size_t)m * 128 + strip * 2 + wn] = ix;
      }
    }
}

// ---- final 128-way argmin per query + gather -----------------------------
__global__ void reduce128(const float* __restrict__ pval, const int* __restrict__ pidx,
                          const float* __restrict__ Y, float* __restrict__ out) {
  const int wid = threadIdx.x >> 6;
  const int lane = threadIdx.x & 63;
  const int q = blockIdx.x * 4 + wid;
  float v = pval[(size_t)q * 128 + lane];
  int ix = pidx[(size_t)q * 128 + lane];
  float v1 = pval[(size_t)q * 128 + 64 + lane];
  int i1 = pidx[(size_t)q * 128 + 64 + lane];
  if (v1 < v || (v1 == v && i1 < ix)) { v = v1; ix = i1; }
#pragma unroll
  for (int off = 32; off > 0; off >>= 1) {
    float ov = __shfl_xor(v, off, 64);
    int oi = __shfl_xor(ix, off, 64);
    if (ov < v || (ov == v && oi < ix)) { v = ov; ix = oi; }
  }
  if (lane < 24) out[(size_t)q * 24 + lane] = Y[(size_t)ix * 24 + lane];
}

// ======================= fp32 fallback (small ws) =========================
#define BK 16
#define PAD 132
__global__ __launch_bounds__(256) void dist_f32(
    const float* __restrict__ x, const float* __restrict__ Xt,
    const float* __restrict__ tt, float* __restrict__ pval, int* __restrict__ pidx) {
  __shared__ float As[BK][PAD];
  __shared__ float Bs[BK][PAD];
  const int t = threadIdx.x;
  const int tx = t & 15;
  const int ty = t >> 4;
  const int qbase = blockIdx.x * 128;
  const int strip = blockIdx.y;
  float bestv[8];
  int besti[8];
#pragma unroll
  for (int i = 0; i < 8; ++i) { bestv[i] = FLT_MAX; besti[i] = 0x7fffffff; }
  for (int tile = 0; tile < 8; ++tile) {
    const int nbase = strip * 1024 + tile * 128;
    float acc[8][8];
#pragma unroll
    for (int i = 0; i < 8; ++i)
#pragma unroll
      for (int j = 0; j < 8; ++j) acc[i][j] = 0.f;
    for (int kt = 0; kt < DIM / BK; ++kt) {
      const int kbase = kt * BK;
      __syncthreads();
#pragma unroll
      for (int it = 0; it < 2; ++it) {
        int idx = t + it * 256;
        int row = idx >> 2;
        int k4 = (idx & 3) << 2;
        float4 va = *(const float4*)(x + (size_t)(qbase + row) * DIM + kbase + k4);
        As[k4 + 0][row] = va.x; As[k4 + 1][row] = va.y;
        As[k4 + 2][row] = va.z; As[k4 + 3][row] = va.w;
        float4 vb = *(const float4*)(Xt + (size_t)(nbase + row) * DIM + kbase + k4);
        Bs[k4 + 0][row] = vb.x; Bs[k4 + 1][row] = vb.y;
        Bs[k4 + 2][row] = vb.z; Bs[k4 + 3][row] = vb.w;
      }
      __syncthreads();
#pragma unroll
      for (int kk = 0; kk < BK; ++kk) {
        float4 a0 = *(const float4*)&As[kk][ty * 4];
        float4 a1 = *(const float4*)&As[kk][64 + ty * 4];
        float4 b0 = *(const float4*)&Bs[kk][tx * 4];
        float4 b1 = *(const float4*)&Bs[kk][64 + tx * 4];
        float a[8] = {a0.x, a0.y, a0.z, a0.w, a1.x, a1.y, a1.z, a1.w};
        float b[8] = {b0.x, b0.y, b0.z, b0.w, b1.x, b1.y, b1.z, b1.w};
#pragma unroll
        for (int i = 0; i < 8; ++i)
#pragma unroll
          for (int j = 0; j < 8; ++j) acc[i][j] = fmaf(a[i], b[j], acc[i][j]);
      }
    }
    int cols[8];
    float ttv[8];
#pragma unroll
    for (int j = 0; j < 8; ++j) {
      cols[j] = nbase + (j < 4 ? tx * 4 + j : 64 + tx * 4 + (j - 4));
      ttv[j] = tt[cols[j]];
    }
#pragma unroll
    for (int i = 0; i < 8; ++i)
#pragma unroll
      for (int j = 0; j < 8; ++j) {
        float s = fmaf(-2.f, acc[i][j], ttv[j]);
        if (s < bestv[i] || (s == bestv[i] && cols[j] < besti[i])) {
          bestv[i] = s; besti[i] = cols[j];
        }
      }
  }
#pragma unroll
  for (int i = 0; i < 8; ++i) {
    float v = bestv[i];
    int ix = besti[i];
#pragma unroll
    for (int off = 1; off < 16; off <<= 1) {
      float ov = __shfl_xor(v, off, 64);
      int oi = __shfl_xor(ix, off, 64);
      if (ov < v || (ov == v && oi < ix)) { v = ov; ix = oi; }
    }
    if (tx == 0) {
      int row = qbase + (i < 4 ? ty * 4 + i : 64 + ty * 4 + (i - 4));
      pval[(size_t)row * 64 + strip] = v;
      pidx[(size_t)row * 64 + strip] = ix;
    }
  }
}

__global__ void reduce64(const float* __restrict__ pval, const int* __restrict__ pidx,
                         const float* __restrict__ Y, float* __restrict__ out) {
  const int wid = threadIdx.x >> 6;
  const int lane = threadIdx.x & 63;
  const int q = blockIdx.x * 4 + wid;
  float v = pval[(size_t)q * 64 + lane];
  int ix = pidx[(size_t)q * 64 + lane];
#pragma unroll
  for (int off = 32; off > 0; off >>= 1) {
    float ov = __shfl_xor(v, off, 64);
    int oi = __shfl_xor(ix, off, 64);
    if (ov < v || (ov == v && oi < ix)) { v = ov; ix = oi; }
  }
  if (lane < 24) out[(size_t)q * 24 + lane] = Y[(size_t)ix * 24 + lane];
}

// ==========================================================================
extern "C" void kernel_launch(void* const* d_in, const int* in_sizes, int n_in,
                              void* d_out, int out_size, void* d_ws, size_t ws_size,
                              hipStream_t stream) {
  const float* x  = (const float*)d_in[0];   // [2048,384]
  const float* Xt = (const float*)d_in[1];   // [65536,384]
  const float* Y  = (const float*)d_in[2];   // [65536,24]
  float* out = (float*)d_out;                // [2048,24]

  // workspace layout (mfma path): th, tl, xh, xl, tt, pval, pidx
  _Float16* th = (_Float16*)d_ws;
  _Float16* tl = th + (size_t)N_T * DIM;
  _Float16* xh = tl + (size_t)N_T * DIM;
  _Float16* xl = xh + (size_t)B_Q * DIM;
  float* tt = (float*)(xl + (size_t)B_Q * DIM);
  float* pval = tt + N_T;
  int* pidx = (int*)(pval + (size_t)B_Q * 128);
  size_t need = (size_t)((char*)(pidx + (size_t)B_Q * 128) - (char*)d_ws);

  if (ws_size >= need) {
    split_kernel<<<(N_T * DIM / 8 + 255) / 256, 256, 0, stream>>>(Xt, th, tl, N_T * DIM / 8);
    split_kernel<<<(B_Q * DIM / 8 + 255) / 256, 256, 0, stream>>>(x, xh, xl, B_Q * DIM / 8);
    tt_kernel<<<N_T / 4, 256, 0, stream>>>(Xt, tt);
    dist_mfma<<<dim3(B_Q / 128, 64), 256, 0, stream>>>(xh, xl, th, tl, tt, pval, pidx);
    reduce128<<<B_Q / 4, 256, 0, stream>>>(pval, pidx, Y, out);
  } else {
    float* tt2 = (float*)d_ws;
    float* pv2 = tt2 + N_T;
    int* pi2 = (int*)(pv2 + (size_t)B_Q * 64);
    tt_kernel<<<N_T / 4, 256, 0, stream>>>(Xt, tt2);
    dist_f32<<<dim3(B_Q / 128, 64), 256, 0, stream>>>(x, Xt, tt2, pv2, pi2);
    reduce64<<<B_Q / 4, 256, 0, stream>>>(pv2, pi2, Y, out);
  }
}

// Round 7
// 484.829 us; speedup vs baseline: 2.6961x; 1.0604x over previous
//
#include <hip/hip_runtime.h>
#include <cfloat>

#define B_Q 2048
#define N_T 65536
#define DIM 384
#define NSTRIPS 32
#define TILES 8               // 256-train tiles per strip (strip = 2048 trains)
#define KSTEPS 12             // 384 / 32
#define TOTAL_STEPS (TILES * KSTEPS)

typedef __attribute__((ext_vector_type(8))) _Float16 f16x8;
typedef __attribute__((ext_vector_type(4))) float f32x4;

// ---- prep: fp32 -> (hi, lo) fp16 split, 8 elems/thread -------------------
__global__ void split_kernel(const float* __restrict__ in, _Float16* __restrict__ hi,
                             _Float16* __restrict__ lo, int n8) {
  int i = blockIdx.x * 256 + threadIdx.x;
  if (i >= n8) return;
  float4 a = ((const float4*)in)[2 * i];
  float4 b = ((const float4*)in)[2 * i + 1];
  float v[8] = {a.x, a.y, a.z, a.w, b.x, b.y, b.z, b.w};
  f16x8 h, l;
#pragma unroll
  for (int j = 0; j < 8; ++j) {
    _Float16 hj = (_Float16)v[j];
    h[j] = hj;
    l[j] = (_Float16)(v[j] - (float)hj);
  }
  *(f16x8*)(hi + 8 * (size_t)i) = h;
  *(f16x8*)(lo + 8 * (size_t)i) = l;
}

// ---- tt[j] = ||X_train[j]||^2 (one wave per row) -------------------------
__global__ void tt_kernel(const float* __restrict__ Xt, float* __restrict__ tt) {
  const int wave = threadIdx.x >> 6;
  const int lane = threadIdx.x & 63;
  const int row = blockIdx.x * 4 + wave;
  const float* p = Xt + (size_t)row * DIM;
  float s = 0.f;
#pragma unroll
  for (int i = 0; i < DIM / 64; ++i) {
    float v = p[lane + 64 * i];
    s = fmaf(v, v, s);
  }
#pragma unroll
  for (int off = 32; off > 0; off >>= 1) s += __shfl_xor(s, off, 64);
  if (lane == 0) tt[row] = s;
}

// ---- fused MFMA cross-GEMM + argmin, 256x256 tile ------------------------
// 512 thr = 8 waves (4m x 2n); wave owns 64 q-rows x 128 t-cols.
// BK=32, single LDS buffer (64KB), T14 pipeline:
//   issue reg-loads(step+1) -> MFMA(step) -> barrier -> ds_write(step+1) -> barrier
// LDS XOR-swizzle (chunk ^= (row>>1)&3) on BOTH write and read: conflict-free.
// fp32-accurate: x.t = xh.th + xh.tl + xl.th (3 MFMAs, same math as r2 pass).
// Per tile: per-lane argmin over nf, 16-lane shfl reduce, redistribute so
// lane L holds the running best for q-row (wm*64+L). 2 regs of state.
__global__ __launch_bounds__(512, 2) void dist_mfma2(
    const _Float16* __restrict__ xh, const _Float16* __restrict__ xl,
    const _Float16* __restrict__ th, const _Float16* __restrict__ tl,
    const float* __restrict__ tt, float* __restrict__ pval, int* __restrict__ pidx) {
  __shared__ __align__(16) char SM[65536];
  const int AH = 0, AL = 16384, BH = 32768, BL = 49152;

  const int t = threadIdx.x;
  const int lane = t & 63;
  const int wid = t >> 6;
  const int wm = wid >> 1, wn = wid & 1;
  const int r15 = lane & 15, g = lane >> 4;
  const int qbase = blockIdx.y * 256;
  const int strip = blockIdx.x;

  // staging geometry: thread t owns rows {r0, r0+128} at k-chunk ch (16B)
  const int r0 = t >> 2, ch = t & 3;
  const int sch = ch ^ ((r0 >> 1) & 3);          // swizzled chunk (same for r0+128)
  const int wo = r0 * 64 + sch * 16;             // byte offset, slot 0
  const size_t aoff = (size_t)(qbase + r0) * DIM + ch * 8;
  const size_t boff = (size_t)(strip * 2048 + r0) * DIM + ch * 8;

  f16x8 sreg[8];
  auto stage_load = [&](int step) {
    int tile = step / KSTEPS;
    int kt = step - tile * KSTEPS;
    size_t a0 = aoff + kt * 32;
    size_t b0 = boff + (size_t)tile * (256 * DIM) + kt * 32;
    sreg[0] = *(const f16x8*)(xh + a0);
    sreg[1] = *(const f16x8*)(xh + a0 + (size_t)128 * DIM);
    sreg[2] = *(const f16x8*)(xl + a0);
    sreg[3] = *(const f16x8*)(xl + a0 + (size_t)128 * DIM);
    sreg[4] = *(const f16x8*)(th + b0);
    sreg[5] = *(const f16x8*)(th + b0 + (size_t)128 * DIM);
    sreg[6] = *(const f16x8*)(tl + b0);
    sreg[7] = *(const f16x8*)(tl + b0 + (size_t)128 * DIM);
  };
  auto stage_write = [&]() {
    *(f16x8*)(SM + AH + wo) = sreg[0];
    *(f16x8*)(SM + AH + wo + 8192) = sreg[1];
    *(f16x8*)(SM + AL + wo) = sreg[2];
    *(f16x8*)(SM + AL + wo + 8192) = sreg[3];
    *(f16x8*)(SM + BH + wo) = sreg[4];
    *(f16x8*)(SM + BH + wo + 8192) = sreg[5];
    *(f16x8*)(SM + BL + wo) = sreg[6];
    *(f16x8*)(SM + BL + wo + 8192) = sreg[7];
  };
  auto frag = [&](int base, int row, int gg) -> f16x8 {
    int off = base + row * 64 + ((gg ^ ((row >> 1) & 3)) << 4);
    return *(const f16x8*)(SM + off);
  };

  f32x4 acc[4][8];
#pragma unroll
  for (int mf = 0; mf < 4; ++mf)
#pragma unroll
    for (int nf = 0; nf < 8; ++nf) acc[mf][nf] = (f32x4){0.f, 0.f, 0.f, 0.f};

  float bestv = FLT_MAX;
  int besti = 0x7fffffff;

  stage_load(0);
  stage_write();
  __syncthreads();

  for (int step = 0; step < TOTAL_STEPS; ++step) {
    const int tile = step / KSTEPS;
    const int kt = step - tile * KSTEPS;
    const bool has_next = (step + 1 < TOTAL_STEPS);
    if (has_next) stage_load(step + 1);   // issue early; lands during MFMA phase

    f16x8 ah[4], al[4];
#pragma unroll
    for (int mf = 0; mf < 4; ++mf) {
      int row = wm * 64 + mf * 16 + r15;
      ah[mf] = frag(AH, row, g);
      al[mf] = frag(AL, row, g);
    }
#pragma unroll
    for (int nf = 0; nf < 8; ++nf) {
      int row = wn * 128 + nf * 16 + r15;
      f16x8 bh = frag(BH, row, g);
      f16x8 bl = frag(BL, row, g);
#pragma unroll
      for (int mf = 0; mf < 4; ++mf) {
        acc[mf][nf] = __builtin_amdgcn_mfma_f32_16x16x32_f16(ah[mf], bh, acc[mf][nf], 0, 0, 0);
        acc[mf][nf] = __builtin_amdgcn_mfma_f32_16x16x32_f16(ah[mf], bl, acc[mf][nf], 0, 0, 0);
        acc[mf][nf] = __builtin_amdgcn_mfma_f32_16x16x32_f16(al[mf], bh, acc[mf][nf], 0, 0, 0);
      }
    }

    if (kt == KSTEPS - 1) {
      // epilogue: s = tt - 2*cross; per-tile argmin; fold into per-lane row state
      const int nb = strip * 2048 + tile * 256;
      float ttv[8];
#pragma unroll
      for (int nf = 0; nf < 8; ++nf) ttv[nf] = tt[nb + wn * 128 + nf * 16 + r15];
#pragma unroll
      for (int mf = 0; mf < 4; ++mf)
#pragma unroll
        for (int j = 0; j < 4; ++j) {
          float v = fmaf(-2.f, acc[mf][0][j], ttv[0]);
          int ix = nb + wn * 128 + r15;
#pragma unroll
          for (int nf = 1; nf < 8; ++nf) {
            float s = fmaf(-2.f, acc[mf][nf][j], ttv[nf]);
            if (s < v) { v = s; ix = nb + wn * 128 + nf * 16 + r15; }  // cols ascend; ties keep lower
          }
          // reduce across the 16 r15-lanes of each g-group (row = mf*16+g*4+j)
#pragma unroll
          for (int off = 1; off < 16; off <<= 1) {
            float ov = __shfl_xor(v, off, 64);
            int oi = __shfl_xor(ix, off, 64);
            if (ov < v || (ov == v && oi < ix)) { v = ov; ix = oi; }
          }
          // redistribute: lane L owns row L = (mf=L>>4)*16 + (g=(L>>2)&3)*4 + (j=L&3)
          float rv = __shfl(v, ((lane >> 2) & 3) << 4, 64);
          int ri = __shfl(ix, ((lane >> 2) & 3) << 4, 64);
          if ((lane >> 4) == mf && (lane & 3) == j) {
            if (rv < bestv || (rv == bestv && ri < besti)) { bestv = rv; besti = ri; }
          }
        }
#pragma unroll
      for (int mf = 0; mf < 4; ++mf)
#pragma unroll
        for (int nf = 0; nf < 8; ++nf) acc[mf][nf] = (f32x4){0.f, 0.f, 0.f, 0.f};
    }

    __syncthreads();                       // all waves done reading LDS(step)
    if (has_next) {
      stage_write();                       // compiler waits vmcnt for sreg here
      __syncthreads();                     // writes visible before next reads
    }
  }

  const int q = qbase + wm * 64 + lane;
  pval[(size_t)q * 64 + strip * 2 + wn] = bestv;
  pidx[(size_t)q * 64 + strip * 2 + wn] = besti;
}

// ---- final 64-way argmin per query + gather ------------------------------
__global__ void reduce64(const float* __restrict__ pval, const int* __restrict__ pidx,
                         const float* __restrict__ Y, float* __restrict__ out) {
  const int wid = threadIdx.x >> 6;
  const int lane = threadIdx.x & 63;
  const int q = blockIdx.x * 4 + wid;
  float v = pval[(size_t)q * 64 + lane];
  int ix = pidx[(size_t)q * 64 + lane];
#pragma unroll
  for (int off = 32; off > 0; off >>= 1) {
    float ov = __shfl_xor(v, off, 64);
    int oi = __shfl_xor(ix, off, 64);
    if (ov < v || (ov == v && oi < ix)) { v = ov; ix = oi; }
  }
  if (lane < 24) out[(size_t)q * 24 + lane] = Y[(size_t)ix * 24 + lane];
}

// ======================= fp32 fallback (small ws) =========================
#define BK 16
#define PAD 132
__global__ __launch_bounds__(256) void dist_f32(
    const float* __restrict__ x, const float* __restrict__ Xt,
    const float* __restrict__ tt, float* __restrict__ pval, int* __restrict__ pidx) {
  __shared__ float As[BK][PAD];
  __shared__ float Bs[BK][PAD];
  const int t = threadIdx.x;
  const int tx = t & 15;
  const int ty = t >> 4;
  const int qbase = blockIdx.x * 128;
  const int strip = blockIdx.y;
  float bestv[8];
  int besti[8];
#pragma unroll
  for (int i = 0; i < 8; ++i) { bestv[i] = FLT_MAX; besti[i] = 0x7fffffff; }
  for (int tile = 0; tile < 8; ++tile) {
    const int nbase = strip * 1024 + tile * 128;
    float acc[8][8];
#pragma unroll
    for (int i = 0; i < 8; ++i)
#pragma unroll
      for (int j = 0; j < 8; ++j) acc[i][j] = 0.f;
    for (int kt = 0; kt < DIM / BK; ++kt) {
      const int kbase = kt * BK;
      __syncthreads();
#pragma unroll
      for (int it = 0; it < 2; ++it) {
        int idx = t + it * 256;
        int row = idx >> 2;
        int k4 = (idx & 3) << 2;
        float4 va = *(const float4*)(x + (size_t)(qbase + row) * DIM + kbase + k4);
        As[k4 + 0][row] = va.x; As[k4 + 1][row] = va.y;
        As[k4 + 2][row] = va.z; As[k4 + 3][row] = va.w;
        float4 vb = *(const float4*)(Xt + (size_t)(nbase + row) * DIM + kbase + k4);
        Bs[k4 + 0][row] = vb.x; Bs[k4 + 1][row] = vb.y;
        Bs[k4 + 2][row] = vb.z; Bs[k4 + 3][row] = vb.w;
      }
      __syncthreads();
#pragma unroll
      for (int kk = 0; kk < BK; ++kk) {
        float4 a0 = *(const float4*)&As[kk][ty * 4];
        float4 a1 = *(const float4*)&As[kk][64 + ty * 4];
        float4 b0 = *(const float4*)&Bs[kk][tx * 4];
        float4 b1 = *(const float4*)&Bs[kk][64 + tx * 4];
        float a[8] = {a0.x, a0.y, a0.z, a0.w, a1.x, a1.y, a1.z, a1.w};
        float b[8] = {b0.x, b0.y, b0.z, b0.w, b1.x, b1.y, b1.z, b1.w};
#pragma unroll
        for (int i = 0; i < 8; ++i)
#pragma unroll
          for (int j = 0; j < 8; ++j) acc[i][j] = fmaf(a[i], b[j], acc[i][j]);
      }
    }
    int cols[8];
    float ttv[8];
#pragma unroll
    for (int j = 0; j < 8; ++j) {
      cols[j] = nbase + (j < 4 ? tx * 4 + j : 64 + tx * 4 + (j - 4));
      ttv[j] = tt[cols[j]];
    }
#pragma unroll
    for (int i = 0; i < 8; ++i)
#pragma unroll
      for (int j = 0; j < 8; ++j) {
        float s = fmaf(-2.f, acc[i][j], ttv[j]);
        if (s < bestv[i] || (s == bestv[i] && cols[j] < besti[i])) {
          bestv[i] = s; besti[i] = cols[j];
        }
      }
  }
#pragma unroll
  for (int i = 0; i < 8; ++i) {
    float v = bestv[i];
    int ix = besti[i];
#pragma unroll
    for (int off = 1; off < 16; off <<= 1) {
      float ov = __shfl_xor(v, off, 64);
      int oi = __shfl_xor(ix, off, 64);
      if (ov < v || (ov == v && oi < ix)) { v = ov; ix = oi; }
    }
    if (tx == 0) {
      int row = qbase + (i < 4 ? ty * 4 + i : 64 + ty * 4 + (i - 4));
      pval[(size_t)row * 64 + strip] = v;
      pidx[(size_t)row * 64 + strip] = ix;
    }
  }
}

// ==========================================================================
extern "C" void kernel_launch(void* const* d_in, const int* in_sizes, int n_in,
                              void* d_out, int out_size, void* d_ws, size_t ws_size,
                              hipStream_t stream) {
  const float* x  = (const float*)d_in[0];   // [2048,384]
  const float* Xt = (const float*)d_in[1];   // [65536,384]
  const float* Y  = (const float*)d_in[2];   // [65536,24]
  float* out = (float*)d_out;                // [2048,24]

  // workspace layout (mfma path): th, tl, xh, xl, tt, pval, pidx
  _Float16* th = (_Float16*)d_ws;
  _Float16* tl = th + (size_t)N_T * DIM;
  _Float16* xh = tl + (size_t)N_T * DIM;
  _Float16* xl = xh + (size_t)B_Q * DIM;
  float* tt = (float*)(xl + (size_t)B_Q * DIM);
  float* pval = tt + N_T;
  int* pidx = (int*)(pval + (size_t)B_Q * 64);
  size_t need = (size_t)((char*)(pidx + (size_t)B_Q * 64) - (char*)d_ws);

  if (ws_size >= need) {
    split_kernel<<<(N_T * DIM / 8 + 255) / 256, 256, 0, stream>>>(Xt, th, tl, N_T * DIM / 8);
    split_kernel<<<(B_Q * DIM / 8 + 255) / 256, 256, 0, stream>>>(x, xh, xl, B_Q * DIM / 8);
    tt_kernel<<<N_T / 4, 256, 0, stream>>>(Xt, tt);
    dist_mfma2<<<dim3(NSTRIPS, B_Q / 256), 512, 0, stream>>>(xh, xl, th, tl, tt, pval, pidx);
    reduce64<<<B_Q / 4, 256, 0, stream>>>(pval, pidx, Y, out);
  } else {
    float* tt2 = (float*)d_ws;
    float* pv2 = tt2 + N_T;
    int* pi2 = (int*)(pv2 + (size_t)B_Q * 64);
    tt_kernel<<<N_T / 4, 256, 0, stream>>>(Xt, tt2);
    dist_f32<<<dim3(B_Q / 128, 64), 256, 0, stream>>>(x, Xt, tt2, pv2, pi2);
    reduce64<<<B_Q / 4, 256, 0, stream>>>(pv2, pi2, Y, out);
  }
}

// Round 8
// 482.600 us; speedup vs baseline: 2.7085x; 1.0046x over previous
//
#include <hip/hip_runtime.h>
#include <cfloat>

#define B_Q 2048
#define N_T 65536
#define DIM 384
#define NSTRIPS 32
#define TILES 8               // 256-train tiles per strip (strip = 2048 trains)
#define KSTEPS 12             // 384 / 32
#define TOTAL_STEPS (TILES * KSTEPS)   // 96

typedef __attribute__((ext_vector_type(8))) _Float16 f16x8;
typedef __attribute__((ext_vector_type(4))) float f32x4;

__device__ __forceinline__ void gload16(const void* g, void* l) {
  __builtin_amdgcn_global_load_lds(
      (const __attribute__((address_space(1))) void*)g,
      (__attribute__((address_space(3))) void*)l, 16, 0, 0);
}

// ---- prep: A-image [qb:8][kt:12][h:2][row:256][chunk:4][8 f16], unswizzled
__global__ void splitA_kernel(const float* __restrict__ x, _Float16* __restrict__ Aimg) {
  int gid = blockIdx.x * 256 + threadIdx.x;      // 8*12*256*4 = 98304
  int chunk = gid & 3;
  int r1 = gid >> 2;
  int row = r1 & 255;
  int r2 = r1 >> 8;
  int kt = r2 % 12;
  int qb = r2 / 12;
  const float* src = x + (size_t)(qb * 256 + row) * DIM + kt * 32 + chunk * 8;
  f16x8 h, l;
#pragma unroll
  for (int j = 0; j < 8; ++j) {
    float v = src[j];
    _Float16 hj = (_Float16)v;
    h[j] = hj;
    l[j] = (_Float16)(v - (float)hj);
  }
  size_t base = ((size_t)(qb * 12 + kt) * 2) * 8192 + row * 32 + chunk * 8;  // f16 units
  *(f16x8*)(Aimg + base) = h;                 // h=0
  *(f16x8*)(Aimg + base + 8192) = l;          // h=1
}

// ---- prep: B-image [tileg:256][kt:12][h:2][rb:2][t:512][16B], swizzle baked in
// image slot t holds row rb*128+(t>>2), source chunk c=(t&3)^(((t>>2)>>1)&3)
__global__ void splitB_kernel(const float* __restrict__ Xt, _Float16* __restrict__ Bimg) {
  int gid = blockIdx.x * 256 + threadIdx.x;      // 3072*2*512 = 3145728
  int t = gid & 511;
  int r1 = gid >> 9;
  int rb = r1 & 1;
  int r2 = r1 >> 1;
  int kt = r2 % 12;
  int tileg = r2 / 12;
  int r0 = t >> 2;
  int c = (t & 3) ^ ((r0 >> 1) & 3);
  int row = tileg * 256 + rb * 128 + r0;
  const float* src = Xt + (size_t)row * DIM + kt * 32 + c * 8;
  f16x8 h, l;
#pragma unroll
  for (int j = 0; j < 8; ++j) {
    float v = src[j];
    _Float16 hj = (_Float16)v;
    h[j] = hj;
    l[j] = (_Float16)(v - (float)hj);
  }
  size_t base = ((size_t)(tileg * 12 + kt) * 4 + rb) * 4096 + t * 8;  // f16 units; +2*4096 per h
  *(f16x8*)(Bimg + base) = h;                   // h=0, rb
  *(f16x8*)(Bimg + base + 8192) = l;            // h=1, rb
}

// ---- tt[j] = ||X_train[j]||^2 (one wave per row) -------------------------
__global__ void tt_kernel(const float* __restrict__ Xt, float* __restrict__ tt) {
  const int wave = threadIdx.x >> 6;
  const int lane = threadIdx.x & 63;
  const int row = blockIdx.x * 4 + wave;
  const float* p = Xt + (size_t)row * DIM;
  float s = 0.f;
#pragma unroll
  for (int i = 0; i < DIM / 64; ++i) {
    float v = p[lane + 64 * i];
    s = fmaf(v, v, s);
  }
#pragma unroll
  for (int off = 32; off > 0; off >>= 1) s += __shfl_xor(s, off, 64);
  if (lane == 0) tt[row] = s;
}

// ---- fused MFMA cross-GEMM + argmin, 256x256 tile, gload_lds dbuf --------
// 512 thr = 8 waves (4m x 2n). B double-buffered in LDS via global_load_lds
// from pre-swizzled images (linear dest + pre-swz source + swz read, rule 21).
// A-frags read directly from global (3MB image, L2-resident, contiguous 1KB).
// One barrier per K-step; stage(s+1) flies during compute(s) -> counted-by-
// construction (never waits fresh loads; syncthreads drains loads issued one
// full phase earlier). Math/epilogue identical to r7 (verified absmax 0).
__global__ __launch_bounds__(512, 2) void dist_mfma3(
    const char* __restrict__ Aimg, const char* __restrict__ Bimg,
    const float* __restrict__ tt, float* __restrict__ pval, int* __restrict__ pidx) {
  __shared__ __align__(16) char SM[2][32768];   // per buf: [h:2][rb:2][8KB]

  const int t = threadIdx.x;
  const int lane = t & 63;
  const int wid = t >> 6;
  const int wm = wid >> 1, wn = wid & 1;
  const int r15 = lane & 15, g = lane >> 4;
  const int strip = blockIdx.x;
  const int qb = blockIdx.y;
  const int qbase = qb * 256;

  const int aoff = (wm * 64 + r15) * 64 + g * 16;   // + mf*1024, + h*16384

  f32x4 acc[4][8];
#pragma unroll
  for (int mf = 0; mf < 4; ++mf)
#pragma unroll
    for (int nf = 0; nf < 8; ++nf) acc[mf][nf] = (f32x4){0.f, 0.f, 0.f, 0.f};

  float bestv = FLT_MAX;
  int besti = 0x7fffffff;

  // B stage: 4 x gload16, zero VGPR round-trip, linear LDS dest
  auto stageB = [&](int s, int buf) {
    int tile = s / KSTEPS;
    int kt = s - tile * KSTEPS;
    const char* base = Bimg + ((size_t)((strip * 8 + tile) * 12 + kt) * 4) * 8192 + t * 16;
    char* dst = &SM[buf][0] + t * 16;
    gload16(base,         dst);            // h0 rb0
    gload16(base + 8192,  dst + 8192);     // h0 rb1
    gload16(base + 16384, dst + 16384);    // h1 rb0
    gload16(base + 24576, dst + 24576);    // h1 rb1
  };

  stageB(0, 0);

  for (int s = 0; s < TOTAL_STEPS; ++s) {
    __syncthreads();                       // drains own vmcnt: stage(s) landed (had a
                                           // full compute phase in flight); block-wide
    if (s + 1 < TOTAL_STEPS) stageB(s + 1, (s + 1) & 1);   // into buffer whose readers
                                                           // (step s-1) are all done
    const int tile = s / KSTEPS;
    const int kt = s - tile * KSTEPS;
    const char* buf = &SM[s & 1][0];

    // A-frags straight from global (L2-hot, contiguous 1KB per frag per wave)
    const char* ak = Aimg + ((size_t)(qb * 12 + kt)) * 32768;
    f16x8 ah[4], al[4];
#pragma unroll
    for (int mf = 0; mf < 4; ++mf) {
      ah[mf] = *(const f16x8*)(ak + aoff + mf * 1024);
      al[mf] = *(const f16x8*)(ak + 16384 + aoff + mf * 1024);
    }
#pragma unroll
    for (int nf = 0; nf < 8; ++nf) {
      int row = wn * 128 + nf * 16 + r15;
      int boff = row * 64 + ((g ^ ((row >> 1) & 3)) << 4);
      f16x8 bh = *(const f16x8*)(buf + boff);
      f16x8 bl = *(const f16x8*)(buf + 16384 + boff);
#pragma unroll
      for (int mf = 0; mf < 4; ++mf) {
        acc[mf][nf] = __builtin_amdgcn_mfma_f32_16x16x32_f16(ah[mf], bh, acc[mf][nf], 0, 0, 0);
        acc[mf][nf] = __builtin_amdgcn_mfma_f32_16x16x32_f16(ah[mf], bl, acc[mf][nf], 0, 0, 0);
        acc[mf][nf] = __builtin_amdgcn_mfma_f32_16x16x32_f16(al[mf], bh, acc[mf][nf], 0, 0, 0);
      }
    }

    if (kt == KSTEPS - 1) {
      // epilogue (verbatim r7, verified): s = tt - 2*cross; fold into per-lane state
      const int nb = strip * 2048 + tile * 256;
      float ttv[8];
#pragma unroll
      for (int nf = 0; nf < 8; ++nf) ttv[nf] = tt[nb + wn * 128 + nf * 16 + r15];
#pragma unroll
      for (int mf = 0; mf < 4; ++mf)
#pragma unroll
        for (int j = 0; j < 4; ++j) {
          float v = fmaf(-2.f, acc[mf][0][j], ttv[0]);
          int ix = nb + wn * 128 + r15;
#pragma unroll
          for (int nf = 1; nf < 8; ++nf) {
            float sv = fmaf(-2.f, acc[mf][nf][j], ttv[nf]);
            if (sv < v) { v = sv; ix = nb + wn * 128 + nf * 16 + r15; }
          }
#pragma unroll
          for (int off = 1; off < 16; off <<= 1) {
            float ov = __shfl_xor(v, off, 64);
            int oi = __shfl_xor(ix, off, 64);
            if (ov < v || (ov == v && oi < ix)) { v = ov; ix = oi; }
          }
          float rv = __shfl(v, ((lane >> 2) & 3) << 4, 64);
          int ri = __shfl(ix, ((lane >> 2) & 3) << 4, 64);
          if ((lane >> 4) == mf && (lane & 3) == j) {
            if (rv < bestv || (rv == bestv && ri < besti)) { bestv = rv; besti = ri; }
          }
        }
#pragma unroll
      for (int mf = 0; mf < 4; ++mf)
#pragma unroll
        for (int nf = 0; nf < 8; ++nf) acc[mf][nf] = (f32x4){0.f, 0.f, 0.f, 0.f};
    }
  }

  const int q = qbase + wm * 64 + lane;
  pval[(size_t)q * 64 + strip * 2 + wn] = bestv;
  pidx[(size_t)q * 64 + strip * 2 + wn] = besti;
}

// ---- final 64-way argmin per query + gather ------------------------------
__global__ void reduce64(const float* __restrict__ pval, const int* __restrict__ pidx,
                         const float* __restrict__ Y, float* __restrict__ out) {
  const int wid = threadIdx.x >> 6;
  const int lane = threadIdx.x & 63;
  const int q = blockIdx.x * 4 + wid;
  float v = pval[(size_t)q * 64 + lane];
  int ix = pidx[(size_t)q * 64 + lane];
#pragma unroll
  for (int off = 32; off > 0; off >>= 1) {
    float ov = __shfl_xor(v, off, 64);
    int oi = __shfl_xor(ix, off, 64);
    if (ov < v || (ov == v && oi < ix)) { v = ov; ix = oi; }
  }
  if (lane < 24) out[(size_t)q * 24 + lane] = Y[(size_t)ix * 24 + lane];
}

// ======================= fp32 fallback (small ws) =========================
#define BK 16
#define PAD 132
__global__ __launch_bounds__(256) void dist_f32(
    const float* __restrict__ x, const float* __restrict__ Xt,
    const float* __restrict__ tt, float* __restrict__ pval, int* __restrict__ pidx) {
  __shared__ float As[BK][PAD];
  __shared__ float Bs[BK][PAD];
  const int t = threadIdx.x;
  const int tx = t & 15;
  const int ty = t >> 4;
  const int qbase = blockIdx.x * 128;
  const int strip = blockIdx.y;
  float bestv[8];
  int besti[8];
#pragma unroll
  for (int i = 0; i < 8; ++i) { bestv[i] = FLT_MAX; besti[i] = 0x7fffffff; }
  for (int tile = 0; tile < 8; ++tile) {
    const int nbase = strip * 1024 + tile * 128;
    float acc[8][8];
#pragma unroll
    for (int i = 0; i < 8; ++i)
#pragma unroll
      for (int j = 0; j < 8; ++j) acc[i][j] = 0.f;
    for (int kt = 0; kt < DIM / BK; ++kt) {
      const int kbase = kt * BK;
      __syncthreads();
#pragma unroll
      for (int it = 0; it < 2; ++it) {
        int idx = t + it * 256;
        int row = idx >> 2;
        int k4 = (idx & 3) << 2;
        float4 va = *(const float4*)(x + (size_t)(qbase + row) * DIM + kbase + k4);
        As[k4 + 0][row] = va.x; As[k4 + 1][row] = va.y;
        As[k4 + 2][row] = va.z; As[k4 + 3][row] = va.w;
        float4 vb = *(const float4*)(Xt + (size_t)(nbase + row) * DIM + kbase + k4);
        Bs[k4 + 0][row] = vb.x; Bs[k4 + 1][row] = vb.y;
        Bs[k4 + 2][row] = vb.z; Bs[k4 + 3][row] = vb.w;
      }
      __syncthreads();
#pragma unroll
      for (int kk = 0; kk < BK; ++kk) {
        float4 a0 = *(const float4*)&As[kk][ty * 4];
        float4 a1 = *(const float4*)&As[kk][64 + ty * 4];
        float4 b0 = *(const float4*)&Bs[kk][tx * 4];
        float4 b1 = *(const float4*)&Bs[kk][64 + tx * 4];
        float a[8] = {a0.x, a0.y, a0.z, a0.w, a1.x, a1.y, a1.z, a1.w};
        float b[8] = {b0.x, b0.y, b0.z, b0.w, b1.x, b1.y, b1.z, b1.w};
#pragma unroll
        for (int i = 0; i < 8; ++i)
#pragma unroll
          for (int j = 0; j < 8; ++j) acc[i][j] = fmaf(a[i], b[j], acc[i][j]);
      }
    }
    int cols[8];
    float ttv[8];
#pragma unroll
    for (int j = 0; j < 8; ++j) {
      cols[j] = nbase + (j < 4 ? tx * 4 + j : 64 + tx * 4 + (j - 4));
      ttv[j] = tt[cols[j]];
    }
#pragma unroll
    for (int i = 0; i < 8; ++i)
#pragma unroll
      for (int j = 0; j < 8; ++j) {
        float s = fmaf(-2.f, acc[i][j], ttv[j]);
        if (s < bestv[i] || (s == bestv[i] && cols[j] < besti[i])) {
          bestv[i] = s; besti[i] = cols[j];
        }
      }
  }
#pragma unroll
  for (int i = 0; i < 8; ++i) {
    float v = bestv[i];
    int ix = besti[i];
#pragma unroll
    for (int off = 1; off < 16; off <<= 1) {
      float ov = __shfl_xor(v, off, 64);
      int oi = __shfl_xor(ix, off, 64);
      if (ov < v || (ov == v && oi < ix)) { v = ov; ix = oi; }
    }
    if (tx == 0) {
      int row = qbase + (i < 4 ? ty * 4 + i : 64 + ty * 4 + (i - 4));
      pval[(size_t)row * 64 + strip] = v;
      pidx[(size_t)row * 64 + strip] = ix;
    }
  }
}

// ==========================================================================
extern "C" void kernel_launch(void* const* d_in, const int* in_sizes, int n_in,
                              void* d_out, int out_size, void* d_ws, size_t ws_size,
                              hipStream_t stream) {
  const float* x  = (const float*)d_in[0];   // [2048,384]
  const float* Xt = (const float*)d_in[1];   // [65536,384]
  const float* Y  = (const float*)d_in[2];   // [65536,24]
  float* out = (float*)d_out;                // [2048,24]

  // workspace layout: Bimg (96MB), Aimg (3MB), tt, pval, pidx
  char* Bimg = (char*)d_ws;
  const size_t BIMG_BYTES = (size_t)256 * 12 * 4 * 8192;        // 100663296
  char* Aimg = Bimg + BIMG_BYTES;
  const size_t AIMG_BYTES = (size_t)8 * 12 * 2 * 16384;         // 3145728
  float* tt = (float*)(Aimg + AIMG_BYTES);
  float* pval = tt + N_T;
  int* pidx = (int*)(pval + (size_t)B_Q * 64);
  size_t need = (size_t)((char*)(pidx + (size_t)B_Q * 64) - (char*)d_ws);

  if (ws_size >= need) {
    splitB_kernel<<<12288, 256, 0, stream>>>(Xt, (_Float16*)Bimg);
    splitA_kernel<<<384, 256, 0, stream>>>(x, (_Float16*)Aimg);
    tt_kernel<<<N_T / 4, 256, 0, stream>>>(Xt, tt);
    dist_mfma3<<<dim3(NSTRIPS, B_Q / 256), 512, 0, stream>>>(Aimg, Bimg, tt, pval, pidx);
    reduce64<<<B_Q / 4, 256, 0, stream>>>(pval, pidx, Y, out);
  } else {
    float* tt2 = (float*)d_ws;
    float* pv2 = tt2 + N_T;
    int* pi2 = (int*)(pv2 + (size_t)B_Q * 64);
    tt_kernel<<<N_T / 4, 256, 0, stream>>>(Xt, tt2);
    dist_f32<<<dim3(B_Q / 128, 64), 256, 0, stream>>>(x, Xt, tt2, pv2, pi2);
    reduce64<<<B_Q / 4, 256, 0, stream>>>(pv2, pi2, Y, out);
  }
}